// Round 1
// 340.356 us; speedup vs baseline: 1.0266x; 1.0266x over previous
//
#include <hip/hip_runtime.h>
#include <math.h>

#define B_   64
#define T_   1024
#define AD   128
#define RD   1024
#define ED   512
#define NF   32
#define KS   31
#define PADW 15

typedef short bf16x8 __attribute__((ext_vector_type(8)));
typedef float f32x4  __attribute__((ext_vector_type(4)));

typedef __attribute__((address_space(1))) unsigned gu32;
typedef __attribute__((address_space(3))) unsigned lu32;

// async global->LDS, 16B per lane. LDS dest = wave-uniform base + lane*16.
__device__ __forceinline__ void gll16(const void* g, void* l) {
  __builtin_amdgcn_global_load_lds(
      (gu32*)(unsigned long long)g,
      (lu32*)(unsigned)(unsigned long long)l, 16, 0, 0);
}

__device__ __forceinline__ short f2bf(float x) {
  union { float f; unsigned u; } v; v.f = x;
  unsigned r = (v.u + 0x7FFFu + ((v.u >> 16) & 1u)) >> 16;  // RNE
  return (short)r;
}

__device__ __forceinline__ float tanh_fast(float x) {
  float t = __expf(2.0f * x);
  return (t - 1.0f) * __builtin_amdgcn_rcpf(t + 1.0f);
}

// ---------------------------------------------------------------------------
// PREP (small now): [0,68) Wk/Wlp bf16; [68,580) conv; [580,644) q_proj.
// keys conversion is FUSED into scores_kernel (saves 134 MB HBM traffic and
// the 82 us latency-bound streaming pass).
__global__ __launch_bounds__(256) void prep_kernel(
    const float* __restrict__ Wk, const float* __restrict__ Wlp,
    const float* __restrict__ awc, const float* __restrict__ Wc,
    const float* __restrict__ query, const float* __restrict__ Wq,
    short* __restrict__ Wk16, short* __restrict__ Wlp16,
    short* __restrict__ loc_g, float* __restrict__ qp) {
  __shared__ float sh_awc[128 + KS - 1];
  __shared__ float sh_wc[NF * KS];
  __shared__ float sh_q[RD];
  __shared__ float sh_red[AD];
  const int blk = blockIdx.x, tid = threadIdx.x;

  if (blk < 68) {
    int p = blk * 256 + tid;
    const float* src; short* dst; int off;
    if (p < 16384) { src = Wk; dst = Wk16; off = p; }
    else           { src = Wlp; dst = Wlp16; off = p - 16384; }
    float4 v = *(const float4*)&src[off * 4];
    short4 h = { f2bf(v.x), f2bf(v.y), f2bf(v.z), f2bf(v.w) };
    *(short4*)&dst[off * 4] = h;
  } else if (blk < 68 + 512) {
    // location conv -> loc_g[(b*T+t)*NF + f] (bf16)
    int cb = blk - 68;
    int b = cb >> 3, t0 = (cb & 7) * 128;
    for (int i = tid; i < NF * KS; i += 256) sh_wc[i] = Wc[i];
    if (tid < 128 + KS - 1) {
      int gt = t0 - PADW + tid;
      sh_awc[tid] = (gt >= 0 && gt < T_) ? awc[b * T_ + gt] : 0.0f;
    }
    __syncthreads();
    const int t = tid & 127, fh = (tid >> 7) * 16;
    for (int fq = 0; fq < 4; ++fq) {
      float s0 = 0.f, s1 = 0.f, s2 = 0.f, s3 = 0.f;
      const float* w0 = &sh_wc[(fh + fq * 4 + 0) * KS];
      const float* w1 = &sh_wc[(fh + fq * 4 + 1) * KS];
      const float* w2 = &sh_wc[(fh + fq * 4 + 2) * KS];
      const float* w3 = &sh_wc[(fh + fq * 4 + 3) * KS];
#pragma unroll
      for (int k = 0; k < KS; ++k) {
        float aw = sh_awc[t + k];
        s0 += w0[k] * aw; s1 += w1[k] * aw; s2 += w2[k] * aw; s3 += w3[k] * aw;
      }
      short4 h = { f2bf(s0), f2bf(s1), f2bf(s2), f2bf(s3) };
      *(short4*)&loc_g[((size_t)(b * T_ + t0 + t)) * NF + fh + fq * 4] = h;
    }
  } else {
    // q_proj[b][a] = dot(query[b], Wq[a]); 2-way k-split
    int b = blk - (68 + 512);
    *(float4*)&sh_q[tid * 4] = *(const float4*)&query[b * RD + tid * 4];
    __syncthreads();
    const int a = tid & 127, kh = tid >> 7;
    const float* wr = &Wq[(size_t)a * RD + kh * 512];
    const float* qr = &sh_q[kh * 512];
    float acc = 0.f;
    for (int e = 0; e < 512; e += 4) {
      float4 w = *(const float4*)&wr[e];
      acc += w.x * qr[e] + w.y * qr[e + 1] + w.z * qr[e + 2] + w.w * qr[e + 3];
    }
    if (kh == 1) sh_red[a] = acc;
    __syncthreads();
    if (kh == 0) qp[b * AD + a] = acc + sh_red[a];
  }
}

// ---------------------------------------------------------------------------
// SCORES: 128t x 128a tile, grid(8,64). 4 waves 2x2 of 64x64.
// A (keys) is now reg-staged DIRECTLY from fp32: global float4 -> f2bf ->
// ds_write_b128 into the SAME XOR-swizzled layout the gll16 path produced
// (slot s of row r holds global 16B-block s^(r&7)), so the read/compute/
// epilogue paths are untouched and numerics are bit-identical to the old
// prep-converted keys16. B (Wk16, prep-converted, L2-resident) stays gll16.
// Register double-buffer (bufA/bufB): loads for chunk kc+1 issue right after
// the post-stage barrier so HBM latency hides under the 32-MFMA compute.
__global__ __launch_bounds__(256, 2) void scores_kernel(
    const float* __restrict__ keys, const short* __restrict__ Wk16,
    const short* __restrict__ Wlp16, const short* __restrict__ loc_g,
    const float* __restrict__ qp, const float* __restrict__ Wa,
    float* __restrict__ scores) {
  __shared__ alignas(16) short As[128 * 64];
  __shared__ alignas(16) short Bs[128 * 64];
  __shared__ float qp_s[AD], wa_s[AD];
  __shared__ float sc_s[128 * 2];

  const int tid = threadIdx.x;
  const int b = blockIdx.y, t0 = blockIdx.x * 128;
  const int lane = tid & 63, wave = tid >> 6;
  const int wm = wave >> 1, wn = wave & 1;
  const int m16 = lane & 15, s4 = lane >> 4;

  // A reg-staging geometry: thread covers rows sr+32i, col 16B-block sg
  const int sr = tid >> 3;                 // 0..31
  const int sg = tid & 7;                  // 0..7
  const int swz = (sg ^ (sr & 7)) * 8;     // XOR-swizzled LDS slot (shorts)
  const float* kA = &keys[((size_t)(b * T_ + t0 + sr)) * ED + sg * 8];

  float4 bufA[8], bufB[8];
  auto LOADA = [&](float4 (&buf)[8], int kc) {
#pragma unroll
    for (int i = 0; i < 4; ++i) {
      const float* p = kA + (size_t)i * 32 * ED + (size_t)kc * 64;
      buf[2 * i]     = *(const float4*)p;
      buf[2 * i + 1] = *(const float4*)(p + 4);
    }
  };
  auto WRITEA = [&](float4 (&buf)[8]) {
#pragma unroll
    for (int i = 0; i < 4; ++i) {
      bf16x8 h = { f2bf(buf[2*i].x),   f2bf(buf[2*i].y),
                   f2bf(buf[2*i].z),   f2bf(buf[2*i].w),
                   f2bf(buf[2*i+1].x), f2bf(buf[2*i+1].y),
                   f2bf(buf[2*i+1].z), f2bf(buf[2*i+1].w) };
      *(bf16x8*)&As[(sr + i * 32) * 64 + swz] = h;
    }
  };

  LOADA(bufA, 0);  // issue chunk-0 keys loads before anything else

  if (tid < AD) { qp_s[tid] = qp[b * AD + tid]; wa_s[tid] = Wa[tid]; }

  // ---- stage loc (A) / Wlp (B): rows of 32 shorts = 4 x 16B blocks ----
  {
    const int r = lane >> 2, cb = lane & 3;  // 16 rows per instr
#pragma unroll
    for (int i = 0; i < 2; ++i) {
      int row = wave * 32 + i * 16;
      gll16(&loc_g[((size_t)(b * T_ + t0 + row + r)) * NF + cb * 8],
            &As[row * 32]);
      gll16(&Wlp16[(row + r) * NF + cb * 8], &Bs[row * 32]);
    }
  }
  __syncthreads();

  f32x4 acc[4][4];
  {  // loc MFMA chunk (K=32), stride-32 plain layout
    bf16x8 af[4], bfr[4];
#pragma unroll
    for (int mt = 0; mt < 4; ++mt)
      af[mt] = *(const bf16x8*)&As[(wm * 64 + mt * 16 + m16) * 32 + s4 * 8];
#pragma unroll
    for (int nt = 0; nt < 4; ++nt)
      bfr[nt] = *(const bf16x8*)&Bs[(wn * 64 + nt * 16 + m16) * 32 + s4 * 8];
#pragma unroll
    for (int mt = 0; mt < 4; ++mt)
#pragma unroll
      for (int nt = 0; nt < 4; ++nt)
        acc[mt][nt] = __builtin_amdgcn_mfma_f32_16x16x32_bf16(
            af[mt], bfr[nt], (f32x4){0.f, 0.f, 0.f, 0.f}, 0, 0, 0);
  }

  // ---- main loop: 8 chunks of BK=64, 2 chunks per iteration ----
  const int r8 = lane >> 3, cb8 = lane & 7;
  const int cbg = cb8 ^ r8;  // XOR swizzle for B's gll16 staging

  auto STAGEB = [&](int kc) {
#pragma unroll
    for (int i = 0; i < 4; ++i) {
      int row = wave * 32 + i * 8;
      gll16(&Wk16[(size_t)(row + r8) * ED + (size_t)kc * 64 + cbg * 8],
            &Bs[row * 64]);
    }
  };
  auto COMPUTE = [&]() {
#pragma unroll
    for (int kk2 = 0; kk2 < 2; ++kk2) {
      const int j = kk2 * 4 + s4;
      const int ca = (j ^ (m16 & 7)) * 8;
      bf16x8 af[4], bfr[4];
#pragma unroll
      for (int mt = 0; mt < 4; ++mt)
        af[mt] = *(const bf16x8*)&As[(wm * 64 + mt * 16 + m16) * 64 + ca];
#pragma unroll
      for (int nt = 0; nt < 4; ++nt)
        bfr[nt] = *(const bf16x8*)&Bs[(wn * 64 + nt * 16 + m16) * 64 + ca];
#pragma unroll
      for (int mt = 0; mt < 4; ++mt)
#pragma unroll
        for (int nt = 0; nt < 4; ++nt)
          acc[mt][nt] = __builtin_amdgcn_mfma_f32_16x16x32_bf16(
              af[mt], bfr[nt], acc[mt][nt], 0, 0, 0);
    }
  };

  for (int kc = 0; kc < 8; kc += 2) {
    __syncthreads();           // waves done reading previous tile
    WRITEA(bufA);              // convert + ds_write_b128 (swizzled)
    STAGEB(kc);
    __syncthreads();           // tile ready (drains vmcnt + lgkmcnt)
    LOADA(bufB, kc + 1);       // overlap next keys loads with compute
    COMPUTE();
    __syncthreads();
    WRITEA(bufB);
    STAGEB(kc + 1);
    __syncthreads();
    if (kc < 6) LOADA(bufA, kc + 2);
    COMPUTE();
  }

  // ---- epilogue: +qp, tanh, Wa-dot, reduce over a ----
  float qv[4], wv[4];
#pragma unroll
  for (int nt = 0; nt < 4; ++nt) {
    int a = wn * 64 + nt * 16 + m16;
    qv[nt] = qp_s[a]; wv[nt] = wa_s[a];
  }
#pragma unroll
  for (int mt = 0; mt < 4; ++mt) {
#pragma unroll
    for (int r = 0; r < 4; ++r) {
      float p = 0.f;
#pragma unroll
      for (int nt = 0; nt < 4; ++nt)
        p += wv[nt] * tanh_fast(acc[mt][nt][r] + qv[nt]);
      p += __shfl_xor(p, 1); p += __shfl_xor(p, 2);
      p += __shfl_xor(p, 4); p += __shfl_xor(p, 8);
      if (m16 == 0) sc_s[(wm * 64 + mt * 16 + s4 * 4 + r) * 2 + wn] = p;
    }
  }
  __syncthreads();
  if (tid < 128)
    scores[(size_t)b * T_ + t0 + tid] = sc_s[tid * 2] + sc_s[tid * 2 + 1];
}

// ---------------------------------------------------------------------------
__global__ __launch_bounds__(256) void softmax_kernel(
    const float* __restrict__ scores, const unsigned char* __restrict__ mask,
    float* __restrict__ attn) {
  const int b = blockIdx.x, tid = threadIdx.x;
  __shared__ float redm[4], reds[4];

  float4 s4 = *(const float4*)&scores[b * T_ + tid * 4];
  uchar4 m4 = *(const uchar4*)&mask[b * T_ + tid * 4];
  if (m4.x) s4.x = -INFINITY;
  if (m4.y) s4.y = -INFINITY;
  if (m4.z) s4.z = -INFINITY;
  if (m4.w) s4.w = -INFINITY;

  float mx = fmaxf(fmaxf(s4.x, s4.y), fmaxf(s4.z, s4.w));
#pragma unroll
  for (int off = 32; off >= 1; off >>= 1) mx = fmaxf(mx, __shfl_xor(mx, off, 64));
  if ((tid & 63) == 0) redm[tid >> 6] = mx;
  __syncthreads();
  mx = fmaxf(fmaxf(redm[0], redm[1]), fmaxf(redm[2], redm[3]));

  float e0 = expf(s4.x - mx), e1 = expf(s4.y - mx);
  float e2 = expf(s4.z - mx), e3 = expf(s4.w - mx);
  float sum = e0 + e1 + e2 + e3;
#pragma unroll
  for (int off = 32; off >= 1; off >>= 1) sum += __shfl_xor(sum, off, 64);
  if ((tid & 63) == 0) reds[tid >> 6] = sum;
  __syncthreads();
  sum = reds[0] + reds[1] + reds[2] + reds[3];

  float inv = 1.0f / sum;
  float4 o4 = { e0 * inv, e1 * inv, e2 * inv, e3 * inv };
  *(float4*)&attn[b * T_ + tid * 4] = o4;
}

// ---------------------------------------------------------------------------
// grid (32,B): 2048 blocks -> 100% wave occupancy; 8 float4 loads batched
// ahead of the fma group so ~8 loads/wave stay in flight (was latency-bound
// at 50% occupancy with a fma-chained loop).
__global__ __launch_bounds__(256) void wvsum_kernel(
    const float* __restrict__ values, const float* __restrict__ attn,
    float* __restrict__ wvp) {
  const int tc = blockIdx.x, b = blockIdx.y, tid = threadIdx.x;
  __shared__ float at_s[32];
  if (tid < 32) at_s[tid] = attn[b * T_ + tc * 32 + tid];
  __syncthreads();
  const int e4 = tid & 127, th = tid >> 7;   // 128 float4 cols x 2 t-halves
  const float* vb =
      values + ((size_t)(b * T_ + tc * 32 + th * 16)) * ED + e4 * 4;
  const float* as = &at_s[th * 16];
  float4 acc = {0.f, 0.f, 0.f, 0.f};
#pragma unroll
  for (int t8 = 0; t8 < 16; t8 += 8) {
    float4 v[8];
#pragma unroll
    for (int u = 0; u < 8; ++u)
      v[u] = *(const float4*)&vb[(size_t)(t8 + u) * ED];
#pragma unroll
    for (int u = 0; u < 8; ++u) {
      float a = as[t8 + u];
      acc.x = fmaf(a, v[u].x, acc.x); acc.y = fmaf(a, v[u].y, acc.y);
      acc.z = fmaf(a, v[u].z, acc.z); acc.w = fmaf(a, v[u].w, acc.w);
    }
  }
  *(float4*)&wvp[((size_t)(b * 64 + tc * 2 + th)) * ED + e4 * 4] = acc;
}

// ---------------------------------------------------------------------------
__global__ __launch_bounds__(256) void context_kernel(
    const float* __restrict__ wvp, const float* __restrict__ Wv,
    float* __restrict__ ctx) {
  const int fq = blockIdx.x, b = blockIdx.y, tid = threadIdx.x;
  __shared__ float wv_s[ED];
  __shared__ float red[128];
  for (int e = tid; e < ED; e += 256) {
    float s = 0.f;
    const float* base = &wvp[(size_t)b * 64 * ED + e];
#pragma unroll 16
    for (int p = 0; p < 64; ++p) s += base[p * ED];
    wv_s[e] = s;
  }
  __syncthreads();
  const int fl = tid & 127, eh = tid >> 7;
  const int f = fq * 128 + fl;
  const float* wr = &Wv[(size_t)f * ED + eh * 256];
  const float* qr = &wv_s[eh * 256];
  float acc = 0.f;
  for (int e = 0; e < 256; e += 4) {
    float4 w = *(const float4*)&wr[e];
    acc += w.x * qr[e] + w.y * qr[e + 1] + w.z * qr[e + 2] + w.w * qr[e + 3];
  }
  if (eh == 1) red[fl] = acc;
  __syncthreads();
  if (eh == 0) ctx[b * ED + f] = acc + red[fl];
}

// ---------------------------------------------------------------------------
extern "C" void kernel_launch(void* const* d_in, const int* in_sizes, int n_in,
                              void* d_out, int out_size, void* d_ws, size_t ws_size,
                              hipStream_t stream) {
  const float* query = (const float*)d_in[0];
  const float* keys  = (const float*)d_in[1];
  const float* values= (const float*)d_in[2];
  const float* awc   = (const float*)d_in[3];
  const unsigned char* mask = (const unsigned char*)d_in[4];
  const float* Wc    = (const float*)d_in[5];
  const float* Wlp   = (const float*)d_in[6];
  const float* Wq    = (const float*)d_in[7];
  const float* Wk    = (const float*)d_in[8];
  const float* Wv    = (const float*)d_in[9];
  const float* Wa    = (const float*)d_in[10];

  float* ctx  = (float*)d_out;              // (64,512)
  float* attn = (float*)d_out + B_ * ED;    // (64,1024)

  float* ws = (float*)d_ws;
  float* qp      = ws;                                     // 8192 f
  float* scoresB = qp + B_ * AD;                           // 65536 f
  float* wvp     = scoresB + B_ * T_;                      // 2097152 f
  short* Wk16    = (short*)(wvp + (size_t)B_ * 64 * ED);   // 65536 sh
  short* Wlp16   = Wk16 + AD * ED;                         // 4096 sh
  short* loc_g   = Wlp16 + AD * NF;                        // 2097152 sh

  prep_kernel<<<68 + 512 + 64, 256, 0, stream>>>(Wk, Wlp, awc, Wc, query, Wq,
                                                 Wk16, Wlp16, loc_g, qp);
  scores_kernel<<<dim3(8, B_), 256, 0, stream>>>(keys, Wk16, Wlp16, loc_g,
                                                 qp, Wa, scoresB);
  softmax_kernel<<<B_, 256, 0, stream>>>(scoresB, mask, attn);
  wvsum_kernel<<<dim3(32, B_), 256, 0, stream>>>(values, attn, wvp);
  context_kernel<<<dim3(4, B_), 256, 0, stream>>>(wvp, Wv, ctx);
}

// Round 2
// 338.441 us; speedup vs baseline: 1.0324x; 1.0057x over previous
//
#include <hip/hip_runtime.h>
#include <math.h>

#define B_   64
#define T_   1024
#define AD   128
#define RD   1024
#define ED   512
#define NF   32
#define KS   31
#define PADW 15

typedef short bf16x8 __attribute__((ext_vector_type(8)));
typedef float f32x4  __attribute__((ext_vector_type(4)));

typedef __attribute__((address_space(1))) unsigned gu32;
typedef __attribute__((address_space(3))) unsigned lu32;

// async global->LDS, 16B per lane. LDS dest = wave-uniform base + lane*16.
__device__ __forceinline__ void gll16(const void* g, void* l) {
  __builtin_amdgcn_global_load_lds(
      (gu32*)(unsigned long long)g,
      (lu32*)(unsigned)(unsigned long long)l, 16, 0, 0);
}

__device__ __forceinline__ short f2bf(float x) {
  union { float f; unsigned u; } v; v.f = x;
  unsigned r = (v.u + 0x7FFFu + ((v.u >> 16) & 1u)) >> 16;  // RNE
  return (short)r;
}

__device__ __forceinline__ float tanh_fast(float x) {
  float t = __expf(2.0f * x);
  return (t - 1.0f) * __builtin_amdgcn_rcpf(t + 1.0f);
}

// counted waitcnt with literal immediates (double-expand for macro args)
#define WAITV_(n)  asm volatile("s_waitcnt vmcnt(" #n ")" ::: "memory")
#define WAITV(n)   WAITV_(n)
#define WAITVL_(n) asm volatile("s_waitcnt vmcnt(" #n ") lgkmcnt(0)" ::: "memory")
#define WAITVL(n)  WAITVL_(n)
#define SB  __builtin_amdgcn_sched_barrier(0)
#define BAR __builtin_amdgcn_s_barrier()

// ---------------------------------------------------------------------------
// PREP: [0,68) Wk/Wlp bf16; [68,580) conv; [580,644) q_proj.
__global__ __launch_bounds__(256) void prep_kernel(
    const float* __restrict__ Wk, const float* __restrict__ Wlp,
    const float* __restrict__ awc, const float* __restrict__ Wc,
    const float* __restrict__ query, const float* __restrict__ Wq,
    short* __restrict__ Wk16, short* __restrict__ Wlp16,
    short* __restrict__ loc_g, float* __restrict__ qp) {
  __shared__ float sh_awc[128 + KS - 1];
  __shared__ float sh_wc[NF * KS];
  __shared__ float sh_q[RD];
  __shared__ float sh_red[AD];
  const int blk = blockIdx.x, tid = threadIdx.x;

  if (blk < 68) {
    int p = blk * 256 + tid;
    const float* src; short* dst; int off;
    if (p < 16384) { src = Wk; dst = Wk16; off = p; }
    else           { src = Wlp; dst = Wlp16; off = p - 16384; }
    float4 v = *(const float4*)&src[off * 4];
    short4 h = { f2bf(v.x), f2bf(v.y), f2bf(v.z), f2bf(v.w) };
    *(short4*)&dst[off * 4] = h;
  } else if (blk < 68 + 512) {
    // location conv -> loc_g[(b*T+t)*NF + f] (bf16)
    int cb = blk - 68;
    int b = cb >> 3, t0 = (cb & 7) * 128;
    for (int i = tid; i < NF * KS; i += 256) sh_wc[i] = Wc[i];
    if (tid < 128 + KS - 1) {
      int gt = t0 - PADW + tid;
      sh_awc[tid] = (gt >= 0 && gt < T_) ? awc[b * T_ + gt] : 0.0f;
    }
    __syncthreads();
    const int t = tid & 127, fh = (tid >> 7) * 16;
    for (int fq = 0; fq < 4; ++fq) {
      float s0 = 0.f, s1 = 0.f, s2 = 0.f, s3 = 0.f;
      const float* w0 = &sh_wc[(fh + fq * 4 + 0) * KS];
      const float* w1 = &sh_wc[(fh + fq * 4 + 1) * KS];
      const float* w2 = &sh_wc[(fh + fq * 4 + 2) * KS];
      const float* w3 = &sh_wc[(fh + fq * 4 + 3) * KS];
#pragma unroll
      for (int k = 0; k < KS; ++k) {
        float aw = sh_awc[t + k];
        s0 += w0[k] * aw; s1 += w1[k] * aw; s2 += w2[k] * aw; s3 += w3[k] * aw;
      }
      short4 h = { f2bf(s0), f2bf(s1), f2bf(s2), f2bf(s3) };
      *(short4*)&loc_g[((size_t)(b * T_ + t0 + t)) * NF + fh + fq * 4] = h;
    }
  } else {
    // q_proj[b][a] = dot(query[b], Wq[a]); 2-way k-split
    int b = blk - (68 + 512);
    *(float4*)&sh_q[tid * 4] = *(const float4*)&query[b * RD + tid * 4];
    __syncthreads();
    const int a = tid & 127, kh = tid >> 7;
    const float* wr = &Wq[(size_t)a * RD + kh * 512];
    const float* qr = &sh_q[kh * 512];
    float acc = 0.f;
    for (int e = 0; e < 512; e += 4) {
      float4 w = *(const float4*)&wr[e];
      acc += w.x * qr[e] + w.y * qr[e + 1] + w.z * qr[e + 2] + w.w * qr[e + 3];
    }
    if (kh == 1) sh_red[a] = acc;
    __syncthreads();
    if (kh == 0) qp[b * AD + a] = acc + sh_red[a];
  }
}

// ---------------------------------------------------------------------------
// SCORES: 128t x 128a tile, grid(8,64). 4 waves 2x2 of 64x64.
// Counted-vmcnt software pipeline (raw s_barrier, NEVER vmcnt(0) mid-loop):
//   keys fp32 loads issued 2 chunks ahead (reg double-buffer, ~1200cy slack),
//   Wk16 gll16 issued 1 chunk ahead into double-buffered Bs (~600cy slack).
// Per-wave vmem issue order is pinned with sched_barrier(0) so the
// hand-derived vmcnt immediates (12/20 steady-state) are exact.
__global__ __launch_bounds__(256, 2) void scores_kernel(
    const float* __restrict__ keys, const short* __restrict__ Wk16,
    const short* __restrict__ Wlp16, const short* __restrict__ loc_g,
    const float* __restrict__ qp, const float* __restrict__ Wa,
    float* __restrict__ scores) {
  __shared__ alignas(16) short As[128 * 64];
  __shared__ alignas(16) short Bs[2][128 * 64];
  __shared__ float qp_s[AD], wa_s[AD];
  __shared__ float sc_s[128 * 2];

  const int tid = threadIdx.x;
  const int b = blockIdx.y, t0 = blockIdx.x * 128;
  const int lane = tid & 63, wave = tid >> 6;
  const int wm = wave >> 1, wn = wave & 1;
  const int m16 = lane & 15, s4 = lane >> 4;

  // A reg-staging geometry: thread covers rows sr+32i, col 16B-block sg
  const int sr = tid >> 3;                 // 0..31
  const int sg = tid & 7;                  // 0..7
  const int swz = (sg ^ (sr & 7)) * 8;     // XOR-swizzled LDS slot (shorts)
  const float* kA = &keys[((size_t)(b * T_ + t0 + sr)) * ED + sg * 8];

  float4 bufA[8], bufB[8];
  auto LOADA = [&](float4 (&buf)[8], int kc) {   // 8 vmem instrs
#pragma unroll
    for (int i = 0; i < 4; ++i) {
      const float* p = kA + (size_t)i * 32 * ED + (size_t)kc * 64;
      buf[2 * i]     = *(const float4*)p;
      buf[2 * i + 1] = *(const float4*)(p + 4);
    }
  };
  auto WRITEA = [&](float4 (&buf)[8]) {          // ds_write_b128 x4
#pragma unroll
    for (int i = 0; i < 4; ++i) {
      bf16x8 h = { f2bf(buf[2*i].x),   f2bf(buf[2*i].y),
                   f2bf(buf[2*i].z),   f2bf(buf[2*i].w),
                   f2bf(buf[2*i+1].x), f2bf(buf[2*i+1].y),
                   f2bf(buf[2*i+1].z), f2bf(buf[2*i+1].w) };
      *(bf16x8*)&As[(sr + i * 32) * 64 + swz] = h;
    }
  };

  const int r8 = lane >> 3, cb8 = lane & 7;
  const int cbg = cb8 ^ r8;  // XOR swizzle for B's gll16 staging
  auto STAGEB = [&](int kc, int half) {          // 4 vmem instrs
#pragma unroll
    for (int i = 0; i < 4; ++i) {
      int row = wave * 32 + i * 8;
      gll16(&Wk16[(size_t)(row + r8) * ED + (size_t)kc * 64 + cbg * 8],
            &Bs[half][row * 64]);
    }
  };
  f32x4 acc[4][4];
  auto COMPUTE = [&](int half) {
#pragma unroll
    for (int kk2 = 0; kk2 < 2; ++kk2) {
      const int j = kk2 * 4 + s4;
      const int ca = (j ^ (m16 & 7)) * 8;
      bf16x8 af[4], bfr[4];
#pragma unroll
      for (int mt = 0; mt < 4; ++mt)
        af[mt] = *(const bf16x8*)&As[(wm * 64 + mt * 16 + m16) * 64 + ca];
#pragma unroll
      for (int nt = 0; nt < 4; ++nt)
        bfr[nt] = *(const bf16x8*)&Bs[half][(wn * 64 + nt * 16 + m16) * 64 + ca];
      __builtin_amdgcn_s_setprio(1);
#pragma unroll
      for (int mt = 0; mt < 4; ++mt)
#pragma unroll
        for (int nt = 0; nt < 4; ++nt)
          acc[mt][nt] = __builtin_amdgcn_mfma_f32_16x16x32_bf16(
              af[mt], bfr[nt], acc[mt][nt], 0, 0, 0);
      __builtin_amdgcn_s_setprio(0);
    }
  };

  // ---- prologue (pinned vmem order: qpwa, Gloc[4], L0[8], G0[4], L1[8]) ----
  if (tid < AD) qp_s[tid] = qp[b * AD + tid];
  else          wa_s[tid - AD] = Wa[tid - AD];
  SB;
  {  // loc -> As, Wlp -> Bs[1] (stride-32 rows; 4 gll16 per thread)
    const int r = lane >> 2, cbl = lane & 3;
#pragma unroll
    for (int i = 0; i < 2; ++i) {
      int row = wave * 32 + i * 16;
      gll16(&loc_g[((size_t)(b * T_ + t0 + row + r)) * NF + cbl * 8],
            &As[row * 32]);
      gll16(&Wlp16[(row + r) * NF + cbl * 8], &Bs[1][row * 32]);
    }
  }
  SB;
  LOADA(bufA, 0); SB;
  STAGEB(0, 0);   SB;
  LOADA(bufB, 1); SB;
  WAITVL(20);     // loc/Wlp staged (L0+G0+L1 = 20 stay outstanding)
  SB; BAR; SB;

  {  // loc MFMA chunk (K=32), stride-32 plain layout
    bf16x8 af[4], bfr[4];
#pragma unroll
    for (int mt = 0; mt < 4; ++mt)
      af[mt] = *(const bf16x8*)&As[(wm * 64 + mt * 16 + m16) * 32 + s4 * 8];
#pragma unroll
    for (int nt = 0; nt < 4; ++nt)
      bfr[nt] = *(const bf16x8*)&Bs[1][(wn * 64 + nt * 16 + m16) * 32 + s4 * 8];
#pragma unroll
    for (int mt = 0; mt < 4; ++mt)
#pragma unroll
      for (int nt = 0; nt < 4; ++nt)
        acc[mt][nt] = __builtin_amdgcn_mfma_f32_16x16x32_bf16(
            af[mt], bfr[nt], (f32x4){0.f, 0.f, 0.f, 0.f}, 0, 0, 0);
  }

  // ---- main loop: 8 chunks, fully unrolled, counted waits ----
  // vmem per chunk i: [W(i)] G(i+1)[4] L(i+2)[8]; PRE waits L(i), MID waits G(i).
#define CHUNK(i, BUF, PRE, MID, DOG, DOL)                    \
  do {                                                       \
    BAR; SB;          /* readers of As / Bs[(i-1)&1] done */ \
    WAITV(PRE); SB;   /* L(i) regs ready */                  \
    WRITEA(BUF); SB;                                         \
    if (DOG) STAGEB((i) + 1, ((i) + 1) & 1);                 \
    SB;                                                      \
    if (DOL) LOADA(BUF, (i) + 2);                            \
    SB;                                                      \
    WAITVL(MID);      /* G(i) landed, ds_writes done */      \
    SB; BAR; SB;                                             \
    COMPUTE((i) & 1);                                        \
  } while (0)

  CHUNK(0, bufA, 12, 20, true,  true);
  CHUNK(1, bufB, 12, 20, true,  true);
  CHUNK(2, bufA, 12, 20, true,  true);
  CHUNK(3, bufB, 12, 20, true,  true);
  CHUNK(4, bufA, 12, 20, true,  true);
  CHUNK(5, bufB, 12, 20, true,  true);
  CHUNK(6, bufA, 12, 12, true,  false);
  CHUNK(7, bufB,  4,  0, false, false);
#undef CHUNK

  __syncthreads();

  // ---- epilogue: +qp, tanh, Wa-dot, reduce over a ----
  float qv[4], wv[4];
#pragma unroll
  for (int nt = 0; nt < 4; ++nt) {
    int a = wn * 64 + nt * 16 + m16;
    qv[nt] = qp_s[a]; wv[nt] = wa_s[a];
  }
#pragma unroll
  for (int mt = 0; mt < 4; ++mt) {
#pragma unroll
    for (int r = 0; r < 4; ++r) {
      float p = 0.f;
#pragma unroll
      for (int nt = 0; nt < 4; ++nt)
        p += wv[nt] * tanh_fast(acc[mt][nt][r] + qv[nt]);
      p += __shfl_xor(p, 1); p += __shfl_xor(p, 2);
      p += __shfl_xor(p, 4); p += __shfl_xor(p, 8);
      if (m16 == 0) sc_s[(wm * 64 + mt * 16 + s4 * 4 + r) * 2 + wn] = p;
    }
  }
  __syncthreads();
  if (tid < 128)
    scores[(size_t)b * T_ + t0 + tid] = sc_s[tid * 2] + sc_s[tid * 2 + 1];
}

// ---------------------------------------------------------------------------
__global__ __launch_bounds__(256) void softmax_kernel(
    const float* __restrict__ scores, const unsigned char* __restrict__ mask,
    float* __restrict__ attn) {
  const int b = blockIdx.x, tid = threadIdx.x;
  __shared__ float redm[4], reds[4];

  float4 s4 = *(const float4*)&scores[b * T_ + tid * 4];
  uchar4 m4 = *(const uchar4*)&mask[b * T_ + tid * 4];
  if (m4.x) s4.x = -INFINITY;
  if (m4.y) s4.y = -INFINITY;
  if (m4.z) s4.z = -INFINITY;
  if (m4.w) s4.w = -INFINITY;

  float mx = fmaxf(fmaxf(s4.x, s4.y), fmaxf(s4.z, s4.w));
#pragma unroll
  for (int off = 32; off >= 1; off >>= 1) mx = fmaxf(mx, __shfl_xor(mx, off, 64));
  if ((tid & 63) == 0) redm[tid >> 6] = mx;
  __syncthreads();
  mx = fmaxf(fmaxf(redm[0], redm[1]), fmaxf(redm[2], redm[3]));

  float e0 = expf(s4.x - mx), e1 = expf(s4.y - mx);
  float e2 = expf(s4.z - mx), e3 = expf(s4.w - mx);
  float sum = e0 + e1 + e2 + e3;
#pragma unroll
  for (int off = 32; off >= 1; off >>= 1) sum += __shfl_xor(sum, off, 64);
  if ((tid & 63) == 0) reds[tid >> 6] = sum;
  __syncthreads();
  sum = reds[0] + reds[1] + reds[2] + reds[3];

  float inv = 1.0f / sum;
  float4 o4 = { e0 * inv, e1 * inv, e2 * inv, e3 * inv };
  *(float4*)&attn[b * T_ + tid * 4] = o4;
}

// ---------------------------------------------------------------------------
// grid (32,B): 2048 blocks -> full occupancy; 8 float4 loads batched ahead
// of the fma group so ~8 loads/wave stay in flight.
__global__ __launch_bounds__(256) void wvsum_kernel(
    const float* __restrict__ values, const float* __restrict__ attn,
    float* __restrict__ wvp) {
  const int tc = blockIdx.x, b = blockIdx.y, tid = threadIdx.x;
  __shared__ float at_s[32];
  if (tid < 32) at_s[tid] = attn[b * T_ + tc * 32 + tid];
  __syncthreads();
  const int e4 = tid & 127, th = tid >> 7;   // 128 float4 cols x 2 t-halves
  const float* vb =
      values + ((size_t)(b * T_ + tc * 32 + th * 16)) * ED + e4 * 4;
  const float* as = &at_s[th * 16];
  float4 acc = {0.f, 0.f, 0.f, 0.f};
#pragma unroll
  for (int t8 = 0; t8 < 16; t8 += 8) {
    float4 v[8];
#pragma unroll
    for (int u = 0; u < 8; ++u)
      v[u] = *(const float4*)&vb[(size_t)(t8 + u) * ED];
#pragma unroll
    for (int u = 0; u < 8; ++u) {
      float a = as[t8 + u];
      acc.x = fmaf(a, v[u].x, acc.x); acc.y = fmaf(a, v[u].y, acc.y);
      acc.z = fmaf(a, v[u].z, acc.z); acc.w = fmaf(a, v[u].w, acc.w);
    }
  }
  *(float4*)&wvp[((size_t)(b * 64 + tc * 2 + th)) * ED + e4 * 4] = acc;
}

// ---------------------------------------------------------------------------
__global__ __launch_bounds__(256) void context_kernel(
    const float* __restrict__ wvp, const float* __restrict__ Wv,
    float* __restrict__ ctx) {
  const int fq = blockIdx.x, b = blockIdx.y, tid = threadIdx.x;
  __shared__ float wv_s[ED];
  __shared__ float red[128];
  for (int e = tid; e < ED; e += 256) {
    float s = 0.f;
    const float* base = &wvp[(size_t)b * 64 * ED + e];
#pragma unroll 16
    for (int p = 0; p < 64; ++p) s += base[p * ED];
    wv_s[e] = s;
  }
  __syncthreads();
  const int fl = tid & 127, eh = tid >> 7;
  const int f = fq * 128 + fl;
  const float* wr = &Wv[(size_t)f * ED + eh * 256];
  const float* qr = &wv_s[eh * 256];
  float acc = 0.f;
  for (int e = 0; e < 256; e += 4) {
    float4 w = *(const float4*)&wr[e];
    acc += w.x * qr[e] + w.y * qr[e + 1] + w.z * qr[e + 2] + w.w * qr[e + 3];
  }
  if (eh == 1) red[fl] = acc;
  __syncthreads();
  if (eh == 0) ctx[b * ED + f] = acc + red[fl];
}

// ---------------------------------------------------------------------------
extern "C" void kernel_launch(void* const* d_in, const int* in_sizes, int n_in,
                              void* d_out, int out_size, void* d_ws, size_t ws_size,
                              hipStream_t stream) {
  const float* query = (const float*)d_in[0];
  const float* keys  = (const float*)d_in[1];
  const float* values= (const float*)d_in[2];
  const float* awc   = (const float*)d_in[3];
  const unsigned char* mask = (const unsigned char*)d_in[4];
  const float* Wc    = (const float*)d_in[5];
  const float* Wlp   = (const float*)d_in[6];
  const float* Wq    = (const float*)d_in[7];
  const float* Wk    = (const float*)d_in[8];
  const float* Wv    = (const float*)d_in[9];
  const float* Wa    = (const float*)d_in[10];

  float* ctx  = (float*)d_out;              // (64,512)
  float* attn = (float*)d_out + B_ * ED;    // (64,1024)

  float* ws = (float*)d_ws;
  float* qp      = ws;                                     // 8192 f
  float* scoresB = qp + B_ * AD;                           // 65536 f
  float* wvp     = scoresB + B_ * T_;                      // 2097152 f
  short* Wk16    = (short*)(wvp + (size_t)B_ * 64 * ED);   // 65536 sh
  short* Wlp16   = Wk16 + AD * ED;                         // 4096 sh
  short* loc_g   = Wlp16 + AD * NF;                        // 2097152 sh

  prep_kernel<<<68 + 512 + 64, 256, 0, stream>>>(Wk, Wlp, awc, Wc, query, Wq,
                                                 Wk16, Wlp16, loc_g, qp);
  scores_kernel<<<dim3(8, B_), 256, 0, stream>>>(keys, Wk16, Wlp16, loc_g,
                                                 qp, Wa, scoresB);
  softmax_kernel<<<B_, 256, 0, stream>>>(scoresB, mask, attn);
  wvsum_kernel<<<dim3(32, B_), 256, 0, stream>>>(values, attn, wvp);
  context_kernel<<<dim3(4, B_), 256, 0, stream>>>(wvp, Wv, ctx);
}